// Round 12
// baseline (2919.387 us; speedup 1.0000x reference)
//
#include <hip/hip_runtime.h>
#include <hip/hip_bf16.h>

#define B_ 128
#define T_ 200
#define H_ 512
#define G_ 2048   // 4*H
#define E_ 300

typedef unsigned short u16;
typedef unsigned int u32;

using f32x4 = __attribute__((ext_vector_type(4))) float;
using s16x8 = __attribute__((ext_vector_type(8))) short;
using u32x2 = __attribute__((ext_vector_type(2))) u32;

__device__ __forceinline__ u16 f2bf(float f) {
  u32 u = __builtin_bit_cast(u32, f);
  u32 r = (u + 0x7fffu + ((u >> 16) & 1u)) >> 16;   // RNE
  return (u16)r;
}
__device__ __forceinline__ float bf2f(u16 s) {
  return __builtin_bit_cast(float, (u32)s << 16);
}

// ---- device-coherent (L1/L2-bypass) memory ops: sc0 sc1 (PROVEN r3-r10) ---
__device__ __forceinline__ s16x8 ld_h16_sc(const void* p) {
  s16x8 r;
  asm volatile("global_load_dwordx4 %0, %1, off sc0 sc1" : "=v"(r) : "v"(p));
  return r;
}
__device__ __forceinline__ void st_h_sc(void* p, u32 v) {   // low 16 bits
  asm volatile("global_store_short %0, %1, off sc0 sc1" :: "v"(p), "v"(v));
}
__device__ __forceinline__ u32 ld_flag_sc(const void* p) {
  u32 r;
  asm volatile("global_load_dword %0, %1, off sc0 sc1\n\ts_waitcnt vmcnt(0)"
               : "=v"(r) : "v"(p) : "memory");
  return r;
}
__device__ __forceinline__ void st_flag_sc(void* p, u32 v) {
  asm volatile("global_store_dword %0, %1, off sc0 sc1" :: "v"(p), "v"(v) : "memory");
}

// ---------------------------------------------------------------------------
// Wih (4H x E f32) -> bf16 padded [4H x 320]
// ---------------------------------------------------------------------------
__global__ __launch_bounds__(256) void wih_cvt(
    const float* __restrict__ W, u16* __restrict__ Wb)
{
  const int idx = blockIdx.x * 256 + threadIdx.x;   // 2048*320 total
  const int row = idx / 320, k = idx - row * 320;
  const float v = (k < E_) ? W[row * E_ + k] : 0.f;
  Wb[idx] = f2bf(v);
}

// ---------------------------------------------------------------------------
// mask bits: mb[t*4 + w] = bit i <- (tok[(w*32+i)*T + t] != 0)
// ---------------------------------------------------------------------------
__global__ __launch_bounds__(64) void mask_k(
    const int* __restrict__ tok, u32* __restrict__ mb)
{
  const int idx = blockIdx.x * 64 + threadIdx.x;
  if (idx >= T_ * 4) return;
  const int t = idx >> 2, w = idx & 3;
  u32 bits = 0;
  for (int i = 0; i < 32; ++i)
    bits |= (tok[(w * 32 + i) * T_ + t] != 0 ? 1u : 0u) << i;
  mb[idx] = bits;
}

// ---------------------------------------------------------------------------
// xg GEMM, output layout xg[m][j 512][q 4] bf16 with m = t*128 + b.
// (verified end-to-end in rounds 6/7/10)
// ---------------------------------------------------------------------------
__global__ __launch_bounds__(256) void xg_gemm(
    const int* __restrict__ tok, const float* __restrict__ emb,
    const u16* __restrict__ Wb, const float* __restrict__ bih,
    const float* __restrict__ bhh, u16* __restrict__ xg)
{
  __shared__ u16 Al[64 * 320];
  __shared__ u16 Bl[32 * 320];
  __shared__ int tks[64];
  const int tid = threadIdx.x;
  const int bx = blockIdx.x;
  const int m0 = bx * 64;            // m = t*128 + b ; block: t = bx>>1, b0 = (bx&1)*64
  if (tid < 64) tks[tid] = tok[((bx & 1) * 64 + tid) * T_ + (bx >> 1)];
  __syncthreads();
  {
    const int row = tid >> 2, part = tid & 3;
    const float* erow = emb + (size_t)tks[row] * E_;
    char* base = (char*)Al + row * 640;
    const int swz = (row & 7) << 4;
#pragma unroll
    for (int i = 0; i < 40; ++i) {
      const int kw = part * 40 + i;
      const int k = kw * 2;
      const float v0 = (k < E_) ? erow[k] : 0.f;
      const float v1 = (k + 1 < E_) ? erow[k + 1] : 0.f;
      *(u32*)(base + ((kw * 4) ^ swz)) = (u32)f2bf(v0) | ((u32)f2bf(v1) << 16);
    }
  }
  __syncthreads();
  const int wv = tid >> 6, ln = tid & 63, lr = ln & 15, lq = ln >> 4;
  const int arow = wv * 16 + lr;
  const char* abase = (const char*)Al + arow * 640;
  const int aswz = (arow & 7) << 4;
  const int brow = tid >> 3, bpart = tid & 7;
  char* bdst = (char*)Bl + brow * 640;
  const int bswz = (brow & 7) << 4;
  const char* b0base = (const char*)Bl + lr * 640;
  const char* b1base = (const char*)Bl + (16 + lr) * 640;
  const int bswz2 = (lr & 7) << 4;

  for (int ni = 0; ni < 8; ++ni) {
    const int n0 = blockIdx.y * 256 + ni * 32;
    {
      const u16* src = Wb + (size_t)(n0 + brow) * 320 + bpart * 40;
#pragma unroll
      for (int i = 0; i < 5; ++i) {
        s16x8 v = *(const s16x8*)(src + i * 8);
        *(s16x8*)(bdst + (((bpart * 5 + i) * 16) ^ bswz)) = v;
      }
    }
    __syncthreads();
    f32x4 acc0 = {0.f, 0.f, 0.f, 0.f}, acc1 = {0.f, 0.f, 0.f, 0.f};
#pragma unroll
    for (int ks = 0; ks < 10; ++ks) {
      const int kb = ks * 64 + lq * 16;
      s16x8 af  = *(const s16x8*)(abase  + (kb ^ aswz));
      s16x8 bf0 = *(const s16x8*)(b0base + (kb ^ bswz2));
      s16x8 bf1 = *(const s16x8*)(b1base + (kb ^ bswz2));
      acc0 = __builtin_amdgcn_mfma_f32_16x16x32_bf16(af, bf0, acc0, 0, 0, 0);
      acc1 = __builtin_amdgcn_mfma_f32_16x16x32_bf16(af, bf1, acc1, 0, 0, 0);
    }
    const int qc = n0 >> 9;            // gate quadrant (uniform per 32-tile)
    const int jA = (n0 & 511) + lr;    // j within quadrant
#pragma unroll
    for (int r = 0; r < 4; ++r) {
      const int m = m0 + wv * 16 + lq * 4 + r;
      const int gA = n0 + lr, gB = n0 + 16 + lr;
      xg[(size_t)m * 2048 + (size_t)jA * 4 + qc]        = f2bf(acc0[r] + bih[gA] + bhh[gA]);
      xg[(size_t)m * 2048 + (size_t)(jA + 16) * 4 + qc] = f2bf(acc1[r] + bih[gB] + bhh[gB]);
    }
    __syncthreads();
  }
}

// ---------------------------------------------------------------------------
// Persistent LSTM recurrence, v12 = r10 protocol, software-pipelined over a
// PAIR of independent batch-groups per WG. 128 WGs x 512 thr: WG = (pair
// 0..3, jt 0..31) serving groups {pair, pair+4} (16 batch rows each).
// Per iteration: phase A (group pair, step t) then phase B (group pair+4,
// step t). While A's h_{t+1} store propagates, the WG executes B's whole
// phase (~2us) -> next iteration's poll A hits immediately: exposed
// store->poll latency ~0. Bf (weights) shared across the pair; state
// (c/mb/red/flags/gxp/mku) duplicated with compile-time ph indexing.
// Per-phase protocol byte-identical to r10 (poll -> bar -> 2 UC loads ->
// 8 MFMA -> red -> bar -> wave0 epilogue -> drain -> flag). red[A]/red[B]
// reuse ordered by the interleaved barriers: read(t) < 2 barriers < write(t+1).
// ---------------------------------------------------------------------------
template<int TRACK_C>
__global__ __launch_bounds__(512, 2) void lstm_rec(
    const u16* __restrict__ xg, const float* __restrict__ Whh,
    u16* __restrict__ hbuf, const float* __restrict__ c0in,
    float* __restrict__ cOut, float* __restrict__ mhOut,
    u32* __restrict__ flags, const u32* __restrict__ maskb)
{
  __shared__ f32x4 red[2][7][4][64];   // 56 KB: [phase][kslice-1][q][lane]
  const int tid = threadIdx.x;
  const int wv = tid >> 6, ln = tid & 63, lr = ln & 15, lq = ln >> 4;
  const int pairI = (int)blockIdx.x >> 5, jt = (int)blockIdx.x & 31;
  const int j0 = jt * 16;
  const int bg0[2] = { pairI * 16, (pairI + 4) * 16 };
  u32* gflags = flags + pairI * 1024;       // 2 phases x 32 flags x 16 pad

  // persistent B frags (shared by both groups):
  // Bf[q][ks] = Whh[q*512+j0+lr][wv*64+ks*32+lq*8 ..+8]
  s16x8 Bf[4][2];
#pragma unroll
  for (int q = 0; q < 4; ++q) {
    const float* wr = Whh + (size_t)(q * H_ + j0 + lr) * H_ + wv * 64 + lq * 8;
#pragma unroll
    for (int ks = 0; ks < 2; ++ks) {
      const float* wp = wr + ks * 32;
      s16x8 f;
#pragma unroll
      for (int i = 0; i < 8; ++i) f[i] = (short)f2bf(wp[i]);
      Bf[q][ks] = f;
    }
  }

  // epilogue state (wave 0): per phase, 4 cells/lane: b = bg0+lq*4+r, j = j0+lr
  float c[2][4], mb[2][4];
#pragma unroll
  for (int ph = 0; ph < 2; ++ph)
#pragma unroll
    for (int r = 0; r < 4; ++r) {
      const int b = bg0[ph] + lq * 4 + r;
      float cv = 0.f;
      if (!TRACK_C && wv == 0) cv = c0in[b * H_ + j0 + lr];
      c[ph][r] = cv;
      mb[ph][r] = TRACK_C ? cv : 0.f;
    }

  const u32* pp[2] = { gflags + (ln & 31) * 16,
                       gflags + 512 + (ln & 31) * 16 };

  for (int t = 0; t < T_; ++t) {
    const u16* hrd = hbuf + (t & 1) * (B_ * H_);
    u16* hwr = hbuf + ((t + 1) & 1) * (B_ * H_);

    // wave 0: prefetch both phases' xg (u32x2 = 4 gates/cell) + mask words
    u32x2 gxp[2][4];
    u32 mku[2];
    if (wv == 0) {
#pragma unroll
      for (int ph = 0; ph < 2; ++ph) {
        mku[ph] = maskb[t * 4 + (bg0[ph] >> 5)] >> (bg0[ph] & 31);
#pragma unroll
        for (int r = 0; r < 4; ++r) {
          const int b = bg0[ph] + lq * 4 + r;
          gxp[ph][r] = *(const u32x2*)(xg + (size_t)(t * 128 + b) * 2048
                                          + (size_t)(j0 + lr) * 4);
        }
      }
    }

#pragma unroll
    for (int ph = 0; ph < 2; ++ph) {
      // wave 0 polls this group's 32 producer flags (latency already hidden
      // by the other phase's work; typically hits on iteration 1)
      if (wv == 0 && t > 0) {
        int guard = 0;
        for (;;) {
          u32 v = ld_flag_sc(pp[ph]);
          if (__all((int)(v >= (u32)t))) break;
          if (++guard > (1 << 22)) break;   // bail out instead of hanging
          __builtin_amdgcn_s_sleep(1);
        }
      }
      __syncthreads();                       // barrier 1: h_t ready
      __builtin_amdgcn_sched_barrier(0);

      // h_t loads: rows = bg0[ph]+lr, k = wv*64 + ks*32 + lq*8
      s16x8 ha0, ha1;
      const u16* hb = hrd + (size_t)(bg0[ph] + lr) * H_ + wv * 64 + lq * 8;
      ha0 = ld_h16_sc(hb);
      ha1 = ld_h16_sc(hb + 32);
      asm volatile("s_waitcnt vmcnt(0)" ::: "memory");
      __builtin_amdgcn_sched_barrier(0);

      f32x4 acc[4];
#pragma unroll
      for (int q = 0; q < 4; ++q) {
        acc[q] = __builtin_amdgcn_mfma_f32_16x16x32_bf16(ha0, Bf[q][0],
                     (f32x4){0.f, 0.f, 0.f, 0.f}, 0, 0, 0);
        acc[q] = __builtin_amdgcn_mfma_f32_16x16x32_bf16(ha1, Bf[q][1], acc[q], 0, 0, 0);
      }

      if (wv > 0) {
#pragma unroll
        for (int q = 0; q < 4; ++q) red[ph][wv - 1][q][ln] = acc[q];
      }
      __syncthreads();                       // barrier 2: red ready
      if (wv == 0) {
#pragma unroll
        for (int kv = 1; kv < 8; ++kv)
#pragma unroll
          for (int q = 0; q < 4; ++q) acc[q] += red[ph][kv - 1][q][ln];
        const bool last = (t == T_ - 1);
#pragma unroll
        for (int r = 0; r < 4; ++r) {
          const int b = bg0[ph] + lq * 4 + r;
          const u32 lo = gxp[ph][r][0], hi = gxp[ph][r][1];
          const float gi = acc[0][r] + bf2f((u16)lo);
          const float gf = acc[1][r] + bf2f((u16)(lo >> 16));
          const float gG = acc[2][r] + bf2f((u16)hi);
          const float go = acc[3][r] + bf2f((u16)(hi >> 16));
          const float si = 1.f / (1.f + __expf(-gi));
          const float sf = 1.f / (1.f + __expf(-gf));
          const float so = 1.f / (1.f + __expf(-go));
          const float tg = 2.f / (1.f + __expf(-2.f * gG)) - 1.f;
          const float cn = sf * c[ph][r] + si * tg;
          const float tc = 2.f / (1.f + __expf(-2.f * cn)) - 1.f;
          const float hn = so * tc;
          c[ph][r] = cn;
          if ((mku[ph] >> (lq * 4 + r)) & 1u) mb[ph][r] = TRACK_C ? cn : hn;
          if (!last) st_h_sc(hwr + (size_t)b * H_ + j0 + lr, (u32)f2bf(hn));
        }
        if (t + 1 < T_) {
          asm volatile("s_waitcnt vmcnt(0)" ::: "memory");   // drain h stores
          if (ln == 0) st_flag_sc(gflags + ph * 512 + jt * 16, (u32)(t + 1));
        }
      }
      // no barrier 3 needed: red[ph] next write is >=2 barriers away
    }
  }

  if (wv == 0) {
#pragma unroll
    for (int ph = 0; ph < 2; ++ph)
#pragma unroll
      for (int r = 0; r < 4; ++r) {
        const int b = bg0[ph] + lq * 4 + r;
        if (TRACK_C) cOut[b * H_ + j0 + lr] = mb[ph][r];
        else         mhOut[b * H_ + j0 + lr] = mb[ph][r];
      }
  }
}

// ---------------------------------------------------------------------------
// head: logits = [mh, sim] @ fcW^T + fcb ; log_softmax
// ---------------------------------------------------------------------------
__global__ __launch_bounds__(128) void final_k(
    const float* __restrict__ mh, const float* __restrict__ sim,
    const float* __restrict__ fcW, const float* __restrict__ fcb,
    float* __restrict__ out)
{
  const int b = threadIdx.x;
  float l[3];
#pragma unroll
  for (int cc = 0; cc < 3; ++cc) {
    const float* wr = fcW + cc * (H_ + 1);
    float s = fcb[cc] + sim[b] * wr[H_];
    for (int j = 0; j < H_; ++j) s += mh[b * H_ + j] * wr[j];
    l[cc] = s;
  }
  const float m = fmaxf(l[0], fmaxf(l[1], l[2]));
  const float lse = m + logf(__expf(l[0] - m) + __expf(l[1] - m) + __expf(l[2] - m));
  out[b * 3 + 0] = l[0] - lse;
  out[b * 3 + 1] = l[1] - lse;
  out[b * 3 + 2] = l[2] - lse;
}

extern "C" void kernel_launch(void* const* d_in, const int* in_sizes, int n_in,
                              void* d_out, int out_size, void* d_ws, size_t ws_size,
                              hipStream_t stream) {
  const int*   prem = (const int*)d_in[0];
  const int*   hypo = (const int*)d_in[1];
  const float* sim  = (const float*)d_in[2];
  const float* emb  = (const float*)d_in[3];
  const float* WihP = (const float*)d_in[4];
  const float* WhhP = (const float*)d_in[5];
  const float* bihP = (const float*)d_in[6];
  const float* bhhP = (const float*)d_in[7];
  const float* WihH = (const float*)d_in[8];
  const float* WhhH = (const float*)d_in[9];
  const float* bihH = (const float*)d_in[10];
  const float* bhhH = (const float*)d_in[11];
  const float* fcW  = (const float*)d_in[12];
  const float* fcb  = (const float*)d_in[13];
  float* out = (float*)d_out;

  char* ws = (char*)d_ws;
  const size_t XG_BYTES = (size_t)B_ * T_ * G_ * 2;       // 104,857,600
  const size_t HB_OFF = XG_BYTES;                         // 2 x 128 x 512 bf16
  const size_t CL_OFF = HB_OFF + (size_t)2 * B_ * H_ * 2;
  const size_t MH_OFF = CL_OFF + (size_t)B_ * H_ * 4;
  const size_t FL_OFF = MH_OFF + (size_t)B_ * H_ * 4;     // 2 x 16 KB flags
  const size_t MK_OFF = FL_OFF + 32768;                   // 2 x 4 KB maskbits
  const size_t WB_OFF = MK_OFF + 8192;
  const size_t NEED   = WB_OFF + (size_t)G_ * 320 * 2;    // ~107 MB
  if (ws_size < NEED) return;  // visible failure instead of OOB corruption

  u16*   xg    = (u16*)ws;
  u16*   hbuf  = (u16*)(ws + HB_OFF);
  float* cLast = (float*)(ws + CL_OFF);
  float* mh    = (float*)(ws + MH_OFF);
  u32*   flagsP = (u32*)(ws + FL_OFF);        // 4 pairs x 2 x 32 x 64B
  u32*   flagsH = flagsP + 4096;
  u32*   maskbP = (u32*)(ws + MK_OFF);        // 200 x 4 u32
  u32*   maskbH = maskbP + 1024;
  u16*   Wb    = (u16*)(ws + WB_OFF);

  hipMemsetAsync(ws + FL_OFF, 0, 32768, stream);          // both flag regions

  dim3 gG(400, 8);
  wih_cvt<<<2560, 256, 0, stream>>>(WihP, Wb);
  mask_k<<<13, 64, 0, stream>>>(prem, maskbP);
  xg_gemm<<<gG, 256, 0, stream>>>(prem, emb, Wb, bihP, bhhP, xg);
  hipMemsetAsync(hbuf, 0, (size_t)B_ * H_ * 2, stream);   // h0 = 0 (buffer 0)
  lstm_rec<1><<<128, 512, 0, stream>>>(xg, WhhP, hbuf, nullptr, cLast, nullptr, flagsP, maskbP);
  wih_cvt<<<2560, 256, 0, stream>>>(WihH, Wb);
  mask_k<<<13, 64, 0, stream>>>(hypo, maskbH);
  xg_gemm<<<gG, 256, 0, stream>>>(hypo, emb, Wb, bihH, bhhH, xg);
  hipMemsetAsync(hbuf, 0, (size_t)B_ * H_ * 2, stream);   // h0 = 0 (buffer 0)
  lstm_rec<0><<<128, 512, 0, stream>>>(xg, WhhH, hbuf, cLast, nullptr, mh, flagsH, maskbH);
  final_k<<<1, 128, 0, stream>>>(mh, sim, fcW, fcb, out);
}

// Round 14
// 2033.788 us; speedup vs baseline: 1.4354x; 1.4354x over previous
//
#include <hip/hip_runtime.h>
#include <hip/hip_bf16.h>

#define B_ 128
#define T_ 200
#define H_ 512
#define G_ 2048   // 4*H
#define E_ 300

typedef unsigned short u16;
typedef unsigned int u32;

using f32x4 = __attribute__((ext_vector_type(4))) float;
using s16x8 = __attribute__((ext_vector_type(8))) short;
using u32x2 = __attribute__((ext_vector_type(2))) u32;

__device__ __forceinline__ u16 f2bf(float f) {
  u32 u = __builtin_bit_cast(u32, f);
  u32 r = (u + 0x7fffu + ((u >> 16) & 1u)) >> 16;   // RNE
  return (u16)r;
}
__device__ __forceinline__ float bf2f(u16 s) {
  return __builtin_bit_cast(float, (u32)s << 16);
}

// ---- device-coherent (L1/L2-bypass) memory ops: sc0 sc1 (PROVEN r3-r12) ---
__device__ __forceinline__ s16x8 ld_h16_sc(const void* p) {
  s16x8 r;
  asm volatile("global_load_dwordx4 %0, %1, off sc0 sc1" : "=v"(r) : "v"(p));
  return r;
}
__device__ __forceinline__ void st_h_sc(void* p, u32 v) {   // low 16 bits
  asm volatile("global_store_short %0, %1, off sc0 sc1" :: "v"(p), "v"(v));
}
__device__ __forceinline__ u32 ld_flag_sc(const void* p) {
  u32 r;
  asm volatile("global_load_dword %0, %1, off sc0 sc1\n\ts_waitcnt vmcnt(0)"
               : "=v"(r) : "v"(p) : "memory");
  return r;
}
__device__ __forceinline__ void st_flag_sc(void* p, u32 v) {
  asm volatile("global_store_dword %0, %1, off sc0 sc1" :: "v"(p), "v"(v) : "memory");
}

// ---------------------------------------------------------------------------
// Wih (4H x E f32) -> bf16 padded [4H x 320]
// ---------------------------------------------------------------------------
__global__ __launch_bounds__(256) void wih_cvt(
    const float* __restrict__ W, u16* __restrict__ Wb)
{
  const int idx = blockIdx.x * 256 + threadIdx.x;   // 2048*320 total
  const int row = idx / 320, k = idx - row * 320;
  const float v = (k < E_) ? W[row * E_ + k] : 0.f;
  Wb[idx] = f2bf(v);
}

// ---------------------------------------------------------------------------
// mask bits: mb[t*4 + w] = bit i <- (tok[(w*32+i)*T + t] != 0)
// ---------------------------------------------------------------------------
__global__ __launch_bounds__(64) void mask_k(
    const int* __restrict__ tok, u32* __restrict__ mb)
{
  const int idx = blockIdx.x * 64 + threadIdx.x;
  if (idx >= T_ * 4) return;
  const int t = idx >> 2, w = idx & 3;
  u32 bits = 0;
  for (int i = 0; i < 32; ++i)
    bits |= (tok[(w * 32 + i) * T_ + t] != 0 ? 1u : 0u) << i;
  mb[idx] = bits;
}

// ---------------------------------------------------------------------------
// xg GEMM, output layout xg[m][j 512][q 4] bf16 with m = t*128 + b.
// (verified end-to-end in rounds 6/7/10)
// ---------------------------------------------------------------------------
__global__ __launch_bounds__(256) void xg_gemm(
    const int* __restrict__ tok, const float* __restrict__ emb,
    const u16* __restrict__ Wb, const float* __restrict__ bih,
    const float* __restrict__ bhh, u16* __restrict__ xg)
{
  __shared__ u16 Al[64 * 320];
  __shared__ u16 Bl[32 * 320];
  __shared__ int tks[64];
  const int tid = threadIdx.x;
  const int bx = blockIdx.x;
  const int m0 = bx * 64;            // m = t*128 + b ; block: t = bx>>1, b0 = (bx&1)*64
  if (tid < 64) tks[tid] = tok[((bx & 1) * 64 + tid) * T_ + (bx >> 1)];
  __syncthreads();
  {
    const int row = tid >> 2, part = tid & 3;
    const float* erow = emb + (size_t)tks[row] * E_;
    char* base = (char*)Al + row * 640;
    const int swz = (row & 7) << 4;
#pragma unroll
    for (int i = 0; i < 40; ++i) {
      const int kw = part * 40 + i;
      const int k = kw * 2;
      const float v0 = (k < E_) ? erow[k] : 0.f;
      const float v1 = (k + 1 < E_) ? erow[k + 1] : 0.f;
      *(u32*)(base + ((kw * 4) ^ swz)) = (u32)f2bf(v0) | ((u32)f2bf(v1) << 16);
    }
  }
  __syncthreads();
  const int wv = tid >> 6, ln = tid & 63, lr = ln & 15, lq = ln >> 4;
  const int arow = wv * 16 + lr;
  const char* abase = (const char*)Al + arow * 640;
  const int aswz = (arow & 7) << 4;
  const int brow = tid >> 3, bpart = tid & 7;
  char* bdst = (char*)Bl + brow * 640;
  const int bswz = (brow & 7) << 4;
  const char* b0base = (const char*)Bl + lr * 640;
  const char* b1base = (const char*)Bl + (16 + lr) * 640;
  const int bswz2 = (lr & 7) << 4;

  for (int ni = 0; ni < 8; ++ni) {
    const int n0 = blockIdx.y * 256 + ni * 32;
    {
      const u16* src = Wb + (size_t)(n0 + brow) * 320 + bpart * 40;
#pragma unroll
      for (int i = 0; i < 5; ++i) {
        s16x8 v = *(const s16x8*)(src + i * 8);
        *(s16x8*)(bdst + (((bpart * 5 + i) * 16) ^ bswz)) = v;
      }
    }
    __syncthreads();
    f32x4 acc0 = {0.f, 0.f, 0.f, 0.f}, acc1 = {0.f, 0.f, 0.f, 0.f};
#pragma unroll
    for (int ks = 0; ks < 10; ++ks) {
      const int kb = ks * 64 + lq * 16;
      s16x8 af  = *(const s16x8*)(abase  + (kb ^ aswz));
      s16x8 bf0 = *(const s16x8*)(b0base + (kb ^ bswz2));
      s16x8 bf1 = *(const s16x8*)(b1base + (kb ^ bswz2));
      acc0 = __builtin_amdgcn_mfma_f32_16x16x32_bf16(af, bf0, acc0, 0, 0, 0);
      acc1 = __builtin_amdgcn_mfma_f32_16x16x32_bf16(af, bf1, acc1, 0, 0, 0);
    }
    const int qc = n0 >> 9;            // gate quadrant (uniform per 32-tile)
    const int jA = (n0 & 511) + lr;    // j within quadrant
#pragma unroll
    for (int r = 0; r < 4; ++r) {
      const int m = m0 + wv * 16 + lq * 4 + r;
      const int gA = n0 + lr, gB = n0 + 16 + lr;
      xg[(size_t)m * 2048 + (size_t)jA * 4 + qc]        = f2bf(acc0[r] + bih[gA] + bhh[gA]);
      xg[(size_t)m * 2048 + (size_t)(jA + 16) * 4 + qc] = f2bf(acc1[r] + bih[gB] + bhh[gB]);
    }
    __syncthreads();
  }
}

// ---------------------------------------------------------------------------
// Persistent LSTM recurrence, v14 = r10 structure (best measured) with
// barrier C removed. 8 batch-groups of 16 x 32 j-slice WGs = 256 WGs x 512.
// Wave wv = K-slice [wv*64,+64): 2 UC h-loads + 8 MFMA per step. Wave 0 =
// epilogue wave: 8-way LDS red gather, 4 cells/lane, h stores, drain, flag.
// Poll: wave 0, tight loop, own group's 32 flags. 2 barriers/step:
//   A (h_t ready) and B (red ready).
// Barrier-C-removal proof: waves>0 write red(t+1) only after barrier A(t+1);
// wave0 joins A(t+1) only after its epilogue read of red(t) -> no overlap.
// h-buffer reuse ordered by flags alone: flag>=t+1 => that WG passed
// vmcnt(0) on its h_t reads (before barrier B(t)) => buf[t&1] is dead
// before any WG can write it at t+1.
// ---------------------------------------------------------------------------
template<int TRACK_C>
__global__ __launch_bounds__(512, 2) void lstm_rec(
    const u16* __restrict__ xg, const float* __restrict__ Whh,
    u16* __restrict__ hbuf, const float* __restrict__ c0in,
    float* __restrict__ cOut, float* __restrict__ mhOut,
    u32* __restrict__ flags, const u32* __restrict__ maskb)
{
  __shared__ f32x4 red[8][4][64];   // 32 KB: [kslice][q][lane]
  const int tid = threadIdx.x;
  const int wv = tid >> 6, ln = tid & 63, lr = ln & 15, lq = ln >> 4;
  const int grp = (int)blockIdx.x >> 5, jt = (int)blockIdx.x & 31;
  const int j0 = jt * 16, bg0 = grp * 16;
  u32* gflags = flags + grp * 512;          // 32 flags x 16 u32 pad

  // persistent B frags: Bf[q][ks] = Whh[q*512+j0+lr][wv*64+ks*32+lq*8 ..+8]
  s16x8 Bf[4][2];
#pragma unroll
  for (int q = 0; q < 4; ++q) {
    const float* wr = Whh + (size_t)(q * H_ + j0 + lr) * H_ + wv * 64 + lq * 8;
#pragma unroll
    for (int ks = 0; ks < 2; ++ks) {
      const float* wp = wr + ks * 32;
      s16x8 f;
#pragma unroll
      for (int i = 0; i < 8; ++i) f[i] = (short)f2bf(wp[i]);
      Bf[q][ks] = f;
    }
  }

  // epilogue state (wave 0): 4 cells/lane: b = bg0 + lq*4 + r, j = j0 + lr
  float c[4], mb[4];
#pragma unroll
  for (int r = 0; r < 4; ++r) {
    const int b = bg0 + lq * 4 + r;
    float cv = 0.f;
    if (!TRACK_C && wv == 0) cv = c0in[b * H_ + j0 + lr];
    c[r] = cv;
    mb[r] = TRACK_C ? cv : 0.f;
  }

  const u32* pp = gflags + (ln & 31) * 16;   // 32 flags, x2 lane duplication
  const int mword = grp >> 1, mshift = (grp & 1) * 16;

  for (int t = 0; t < T_; ++t) {
    const u16* hrd = hbuf + (t & 1) * (B_ * H_);
    u16* hwr = hbuf + ((t + 1) & 1) * (B_ * H_);

    // wave 0: prefetch xg (u32x2 = 4 gates/cell) + mask word (cached loads)
    u32x2 gxp[4];
    u32 mku = 0;
    if (wv == 0) {
      mku = maskb[t * 4 + mword] >> mshift;
#pragma unroll
      for (int r = 0; r < 4; ++r) {
        const int b = bg0 + lq * 4 + r;
        gxp[r] = *(const u32x2*)(xg + (size_t)(t * 128 + b) * 2048
                                    + (size_t)(j0 + lr) * 4);
      }
      // poll the group's 32 producer flags (tight loop)
      if (t > 0) {
        int guard = 0;
        for (;;) {
          u32 v = ld_flag_sc(pp);
          if (__all((int)(v >= (u32)t))) break;
          if (++guard > (1 << 22)) break;   // bail out instead of hanging
          __builtin_amdgcn_s_sleep(1);
        }
      }
    }
    __syncthreads();                         // barrier A: h_t ready
    __builtin_amdgcn_sched_barrier(0);

    // h_t loads (coherent): rows = bg0+lr, k = wv*64 + ks*32 + lq*8
    s16x8 ha0, ha1;
    const u16* hb = hrd + (size_t)(bg0 + lr) * H_ + wv * 64 + lq * 8;
    ha0 = ld_h16_sc(hb);
    ha1 = ld_h16_sc(hb + 32);
    asm volatile("s_waitcnt vmcnt(0)" ::: "memory");
    __builtin_amdgcn_sched_barrier(0);

    f32x4 acc[4];
#pragma unroll
    for (int q = 0; q < 4; ++q) {
      acc[q] = __builtin_amdgcn_mfma_f32_16x16x32_bf16(ha0, Bf[q][0],
                   (f32x4){0.f, 0.f, 0.f, 0.f}, 0, 0, 0);
      acc[q] = __builtin_amdgcn_mfma_f32_16x16x32_bf16(ha1, Bf[q][1], acc[q], 0, 0, 0);
    }

    if (wv > 0) {
#pragma unroll
      for (int q = 0; q < 4; ++q) red[wv][q][ln] = acc[q];
    }
    __syncthreads();                         // barrier B: red ready
    if (wv == 0) {
#pragma unroll
      for (int kv = 1; kv < 8; ++kv)
#pragma unroll
        for (int q = 0; q < 4; ++q) acc[q] += red[kv][q][ln];
      const bool last = (t == T_ - 1);
#pragma unroll
      for (int r = 0; r < 4; ++r) {
        const int b = bg0 + lq * 4 + r;
        const u32 lo = gxp[r][0], hi = gxp[r][1];
        const float gi = acc[0][r] + bf2f((u16)lo);
        const float gf = acc[1][r] + bf2f((u16)(lo >> 16));
        const float gG = acc[2][r] + bf2f((u16)hi);
        const float go = acc[3][r] + bf2f((u16)(hi >> 16));
        const float si = 1.f / (1.f + __expf(-gi));
        const float sf = 1.f / (1.f + __expf(-gf));
        const float so = 1.f / (1.f + __expf(-go));
        const float tg = 2.f / (1.f + __expf(-2.f * gG)) - 1.f;
        const float cn = sf * c[r] + si * tg;
        const float tc = 2.f / (1.f + __expf(-2.f * cn)) - 1.f;
        const float hn = so * tc;
        c[r] = cn;
        if ((mku >> (lq * 4 + r)) & 1u) mb[r] = TRACK_C ? cn : hn;
        if (!last) st_h_sc(hwr + (size_t)b * H_ + j0 + lr, (u32)f2bf(hn));
      }
      if (t + 1 < T_) {
        asm volatile("s_waitcnt vmcnt(0)" ::: "memory");   // drain h stores
        if (ln == 0) st_flag_sc(gflags + jt * 16, (u32)(t + 1));
      }
    }
    // barrier C removed (see proof in header comment)
  }

  if (wv == 0) {
#pragma unroll
    for (int r = 0; r < 4; ++r) {
      const int b = bg0 + lq * 4 + r;
      if (TRACK_C) cOut[b * H_ + j0 + lr] = mb[r];
      else         mhOut[b * H_ + j0 + lr] = mb[r];
    }
  }
}

// ---------------------------------------------------------------------------
// head: logits = [mh, sim] @ fcW^T + fcb ; log_softmax
// ---------------------------------------------------------------------------
__global__ __launch_bounds__(128) void final_k(
    const float* __restrict__ mh, const float* __restrict__ sim,
    const float* __restrict__ fcW, const float* __restrict__ fcb,
    float* __restrict__ out)
{
  const int b = threadIdx.x;
  float l[3];
#pragma unroll
  for (int cc = 0; cc < 3; ++cc) {
    const float* wr = fcW + cc * (H_ + 1);
    float s = fcb[cc] + sim[b] * wr[H_];
    for (int j = 0; j < H_; ++j) s += mh[b * H_ + j] * wr[j];
    l[cc] = s;
  }
  const float m = fmaxf(l[0], fmaxf(l[1], l[2]));
  const float lse = m + logf(__expf(l[0] - m) + __expf(l[1] - m) + __expf(l[2] - m));
  out[b * 3 + 0] = l[0] - lse;
  out[b * 3 + 1] = l[1] - lse;
  out[b * 3 + 2] = l[2] - lse;
}

extern "C" void kernel_launch(void* const* d_in, const int* in_sizes, int n_in,
                              void* d_out, int out_size, void* d_ws, size_t ws_size,
                              hipStream_t stream) {
  const int*   prem = (const int*)d_in[0];
  const int*   hypo = (const int*)d_in[1];
  const float* sim  = (const float*)d_in[2];
  const float* emb  = (const float*)d_in[3];
  const float* WihP = (const float*)d_in[4];
  const float* WhhP = (const float*)d_in[5];
  const float* bihP = (const float*)d_in[6];
  const float* bhhP = (const float*)d_in[7];
  const float* WihH = (const float*)d_in[8];
  const float* WhhH = (const float*)d_in[9];
  const float* bihH = (const float*)d_in[10];
  const float* bhhH = (const float*)d_in[11];
  const float* fcW  = (const float*)d_in[12];
  const float* fcb  = (const float*)d_in[13];
  float* out = (float*)d_out;

  char* ws = (char*)d_ws;
  const size_t XG_BYTES = (size_t)B_ * T_ * G_ * 2;       // 104,857,600
  const size_t HB_OFF = XG_BYTES;                         // 2 x 128 x 512 bf16
  const size_t CL_OFF = HB_OFF + (size_t)2 * B_ * H_ * 2;
  const size_t MH_OFF = CL_OFF + (size_t)B_ * H_ * 4;
  const size_t FL_OFF = MH_OFF + (size_t)B_ * H_ * 4;     // 2 x 16 KB flags
  const size_t MK_OFF = FL_OFF + 32768;                   // 2 x 4 KB maskbits
  const size_t WB_OFF = MK_OFF + 8192;
  const size_t NEED   = WB_OFF + (size_t)G_ * 320 * 2;    // ~107 MB
  if (ws_size < NEED) return;  // visible failure instead of OOB corruption

  u16*   xg    = (u16*)ws;
  u16*   hbuf  = (u16*)(ws + HB_OFF);
  float* cLast = (float*)(ws + CL_OFF);
  float* mh    = (float*)(ws + MH_OFF);
  u32*   flagsP = (u32*)(ws + FL_OFF);        // 8 grp x 32 x 64B
  u32*   flagsH = flagsP + 4096;
  u32*   maskbP = (u32*)(ws + MK_OFF);        // 200 x 4 u32
  u32*   maskbH = maskbP + 1024;
  u16*   Wb    = (u16*)(ws + WB_OFF);

  hipMemsetAsync(ws + FL_OFF, 0, 32768, stream);          // both flag regions

  dim3 gG(400, 8);
  wih_cvt<<<2560, 256, 0, stream>>>(WihP, Wb);
  mask_k<<<13, 64, 0, stream>>>(prem, maskbP);
  xg_gemm<<<gG, 256, 0, stream>>>(prem, emb, Wb, bihP, bhhP, xg);
  hipMemsetAsync(hbuf, 0, (size_t)B_ * H_ * 2, stream);   // h0 = 0 (buffer 0)
  lstm_rec<1><<<256, 512, 0, stream>>>(xg, WhhP, hbuf, nullptr, cLast, nullptr, flagsP, maskbP);
  wih_cvt<<<2560, 256, 0, stream>>>(WihH, Wb);
  mask_k<<<13, 64, 0, stream>>>(hypo, maskbH);
  xg_gemm<<<gG, 256, 0, stream>>>(hypo, emb, Wb, bihH, bhhH, xg);
  hipMemsetAsync(hbuf, 0, (size_t)B_ * H_ * 2, stream);   // h0 = 0 (buffer 0)
  lstm_rec<0><<<256, 512, 0, stream>>>(xg, WhhH, hbuf, cLast, nullptr, mh, flagsH, maskbH);
  final_k<<<1, 128, 0, stream>>>(mh, sim, fcW, fcb, out);
}